// Round 11
// baseline (161.928 us; speedup 1.0000x reference)
//
#include <hip/hip_runtime.h>

// VQ codebook: z_e [32,64,64,64] f32 (B,C,W,H), emb [1024,64] f32.
// Outputs: quantized [32,64,64,64] f32, indices [131072] (as f32), vq_loss [1].
//
// R11 = R10 with ONE structural change in the scan: e-tiles go through a
// double-buffered LDS stage (global_load_lds, m97/T3 2-phase pattern).
// Stage of tile ct+1 is issued at the top of iteration ct into buf^1; compute
// reads buf; ONE barrier per iteration (compiler's vmcnt drain sits after the
// MFMA+epilogue, hiding L2 latency). Cuts 4-wave-redundant e traffic 4x
// (1.07GB -> 268MB). Staged bytes/layout identical to R8's proven path;
// MFMA, epilogue, rescue, merge, loss all R10 verbatim.

#define CDIM   64
#define KCODES 1024
#define NPTS   131072
#define WH     4096
#define CWH    262144
#define CTILES (KCODES / 16)     // 64
#define DELTA  0.02f

typedef __attribute__((ext_vector_type(4))) float f32x4;
typedef __attribute__((ext_vector_type(8))) short bf16x8;

__device__ inline unsigned short f2bf(float f) {
    unsigned u = __float_as_uint(f);
    return (unsigned short)((u + 0x7FFFu + ((u >> 16) & 1u)) >> 16);
}
__device__ inline float bf2f(unsigned short h) {
    return __uint_as_float(((unsigned)h) << 16);
}

// ---------- prep: E[k]=||e_k||^2 (exact, R1 order) + bf16 hi/lo swizzle + cnt=0 ----------
__global__ __launch_bounds__(256) void vq_prep(const float* __restrict__ emb,
                                               unsigned short* __restrict__ e_swz,
                                               float* __restrict__ E,
                                               int* __restrict__ cnt) {
    int c = blockIdx.x * 256 + threadIdx.x;   // code
    if (c == 0) cnt[0] = 0;
    if (c >= KCODES) return;

    const float4* e4 = (const float4*)(emb + c * CDIM);
    float s = 0.f;
#pragma unroll
    for (int i = 0; i < CDIM / 4; ++i) {
        float4 v = e4[i];
        s = fmaf(v.x, v.x, s); s = fmaf(v.y, v.y, s);
        s = fmaf(v.z, v.z, s); s = fmaf(v.w, v.w, s);
    }
    E[c] = s;

    int ct = c >> 4, col = c & 15;
#pragma unroll
    for (int kh = 0; kh < 2; ++kh)
#pragma unroll
        for (int g = 0; g < 4; ++g) {
            int lane = (g << 4) | col;
            size_t bh = ((size_t)(ct * 2 + 0) * 2 + kh) * 512 + (size_t)lane * 8;
            size_t bl = ((size_t)(ct * 2 + 1) * 2 + kh) * 512 + (size_t)lane * 8;
#pragma unroll
            for (int j = 0; j < 8; ++j) {
                float v = emb[c * CDIM + kh * 32 + g * 8 + j];
                unsigned short hi = f2bf(v);
                unsigned short lo = f2bf(v - bf2f(hi));
                e_swz[bh + j] = hi;
                e_swz[bl + j] = lo;
            }
        }
}

// ---------- MFMA scan: 128 points/block, double-buffered LDS e-tiles ----------
__global__ __launch_bounds__(256) void vq_scan_mfma(const float* __restrict__ z_e,
                                                    const unsigned short* __restrict__ e_swz,
                                                    const float* __restrict__ E,
                                                    int* __restrict__ bestk,
                                                    int* __restrict__ flagA) {
    const int tid = threadIdx.x;
    const int n0  = blockIdx.x * 128;
    const int b   = n0 >> 12;
    const int wh0 = n0 & 4095;

    __shared__ unsigned short zfrag[8][2][2][512];   // 32 KB
    __shared__ unsigned short se[2][2048];           // 2 x 4 KB e-tile double buffer

    const int lane = tid & 63;
    const int w    = tid >> 6;

    // Issue stage of tile 0 into buf 0 right away (completes by the barrier).
    // Per wave: 64 lanes x 16B = 1KB chunk w; dst wave-uniform, lane*16 appended.
    {
        const unsigned short* gsrc = e_swz + (size_t)w * 512 + (size_t)lane * 8;
        auto* dst = (__attribute__((address_space(3))) void*)&se[0][w * 512];
        __builtin_amdgcn_global_load_lds(
            (const __attribute__((address_space(1))) void*)gsrc, dst, 16, 0, 0);
    }

    const float* zp = z_e + (size_t)b * CWH + wh0;
#pragma unroll 4
    for (int i = 0; i < 32; ++i) {
        int flat = i * 256 + tid;
        int c = flat >> 7, p = flat & 127;
        float v = zp[(size_t)c * WH + p];
        unsigned short hi = f2bf(v);
        unsigned short lo = f2bf(v - bf2f(hi));
        int slot = ((((c & 31) >> 3) << 4) | (p & 15)) * 8 + (c & 7);
        zfrag[p >> 4][0][c >> 5][slot] = hi;
        zfrag[p >> 4][1][c >> 5][slot] = lo;
    }
    __syncthreads();   // zfrag writes + tile-0 DMA both drained here

    bf16x8 zf[2][2][2];
#pragma unroll
    for (int pt = 0; pt < 2; ++pt)
#pragma unroll
        for (int s = 0; s < 2; ++s)
#pragma unroll
            for (int kh = 0; kh < 2; ++kh)
                zf[pt][s][kh] = *(const bf16x8*)&zfrag[2 * w + pt][s][kh][lane * 8];

    const int eoff = ((lane >> 4) << 2);

    float m1a = 1e30f, m2a = 1e30f; int k1a = 0;
    float m1b = 1e30f, m2b = 1e30f; int k1b = 0;

    f32x4 Ev = *(const f32x4*)(E + eoff);

    for (int ct = 0; ct < CTILES; ++ct) {
        // issue stage of tile ct+1 into the other buffer (wraps on last iter)
        const int ctn = (ct + 1) & 63;
        {
            const unsigned short* gsrc =
                e_swz + (size_t)ctn * 2048 + (size_t)w * 512 + (size_t)lane * 8;
            auto* dst = (__attribute__((address_space(3))) void*)&se[(ct + 1) & 1][w * 512];
            __builtin_amdgcn_global_load_lds(
                (const __attribute__((address_space(1))) void*)gsrc, dst, 16, 0, 0);
        }
        f32x4 Ep = *(const f32x4*)(E + ctn * 16 + eoff);

        // read current tile (broadcast ds_read_b128, staged layout == R7's linear chunks)
        const unsigned short* cur = se[ct & 1];
        bf16x8 eh0 = *(const bf16x8*)&cur[0 * 512 + lane * 8];
        bf16x8 eh1 = *(const bf16x8*)&cur[1 * 512 + lane * 8];
        bf16x8 el0 = *(const bf16x8*)&cur[2 * 512 + lane * 8];
        bf16x8 el1 = *(const bf16x8*)&cur[3 * 512 + lane * 8];

        f32x4 acc0 = {0.f, 0.f, 0.f, 0.f};
        f32x4 acc1 = {0.f, 0.f, 0.f, 0.f};
        acc0 = __builtin_amdgcn_mfma_f32_16x16x32_bf16(eh0, zf[0][0][0], acc0, 0, 0, 0);
        acc0 = __builtin_amdgcn_mfma_f32_16x16x32_bf16(eh1, zf[0][0][1], acc0, 0, 0, 0);
        acc0 = __builtin_amdgcn_mfma_f32_16x16x32_bf16(eh0, zf[0][1][0], acc0, 0, 0, 0);
        acc0 = __builtin_amdgcn_mfma_f32_16x16x32_bf16(eh1, zf[0][1][1], acc0, 0, 0, 0);
        acc0 = __builtin_amdgcn_mfma_f32_16x16x32_bf16(el0, zf[0][0][0], acc0, 0, 0, 0);
        acc0 = __builtin_amdgcn_mfma_f32_16x16x32_bf16(el1, zf[0][0][1], acc0, 0, 0, 0);
        acc1 = __builtin_amdgcn_mfma_f32_16x16x32_bf16(eh0, zf[1][0][0], acc1, 0, 0, 0);
        acc1 = __builtin_amdgcn_mfma_f32_16x16x32_bf16(eh1, zf[1][0][1], acc1, 0, 0, 0);
        acc1 = __builtin_amdgcn_mfma_f32_16x16x32_bf16(eh0, zf[1][1][0], acc1, 0, 0, 0);
        acc1 = __builtin_amdgcn_mfma_f32_16x16x32_bf16(eh1, zf[1][1][1], acc1, 0, 0, 0);
        acc1 = __builtin_amdgcn_mfma_f32_16x16x32_bf16(el0, zf[1][0][0], acc1, 0, 0, 0);
        acc1 = __builtin_amdgcn_mfma_f32_16x16x32_bf16(el1, zf[1][0][1], acc1, 0, 0, 0);

        // epilogue: R8/R10's if/else verbatim
        const int kb = ct * 16 + eoff;
#pragma unroll
        for (int i = 0; i < 4; ++i) {
            float s0 = fmaf(-2.0f, acc0[i], Ev[i]);
            if (s0 < m1a) { m2a = m1a; m1a = s0; k1a = kb + i; } else m2a = fminf(m2a, s0);
            float s1 = fmaf(-2.0f, acc1[i], Ev[i]);
            if (s1 < m1b) { m2b = m1b; m1b = s1; k1b = kb + i; } else m2b = fminf(m2b, s1);
        }

        Ev = Ep;
        __syncthreads();   // next tile staged + all waves done with cur
    }

#pragma unroll
    for (int d = 16; d <= 32; d <<= 1) {
        float om1 = __shfl_xor(m1a, d); int ok1 = __shfl_xor(k1a, d); float om2 = __shfl_xor(m2a, d);
        bool take = (om1 < m1a) || (om1 == m1a && ok1 < k1a);
        float nm2 = take ? fminf(m1a, om2) : fminf(m2a, om1);
        if (take) { m1a = om1; k1a = ok1; }
        m2a = nm2;
        om1 = __shfl_xor(m1b, d); ok1 = __shfl_xor(k1b, d); om2 = __shfl_xor(m2b, d);
        take = (om1 < m1b) || (om1 == m1b && ok1 < k1b);
        nm2 = take ? fminf(m1b, om2) : fminf(m2b, om1);
        if (take) { m1b = om1; k1b = ok1; }
        m2b = nm2;
    }

    if (lane < 16) {
        int na  = n0 + (2 * w + 0) * 16 + lane;
        int nb_ = n0 + (2 * w + 1) * 16 + lane;
        bestk[na]  = k1a; flagA[na]  = (m2a - m1a <= DELTA) ? 1 : 0;
        bestk[nb_] = k1b; flagA[nb_] = (m2b - m1b <= DELTA) ? 1 : 0;
    }
}

// ---------- rescue plumbing (R10 verbatim) ----------
__global__ __launch_bounds__(256) void vq_compact(const int* __restrict__ flagA,
                                                  int* __restrict__ list,
                                                  int* __restrict__ cnt) {
    int n = blockIdx.x * 256 + threadIdx.x;
    if (n < NPTS && flagA[n]) { int p = atomicAdd(cnt, 1); list[p] = n; }
}

// Wave-parallel exact f32 rescue (R1-bit-identical per-k arithmetic).
__global__ __launch_bounds__(256) void vq_rescue(const float* __restrict__ z_e,
                                                 const float* __restrict__ emb,
                                                 const float* __restrict__ E,
                                                 const int* __restrict__ list,
                                                 const int* __restrict__ cnt,
                                                 int* __restrict__ bestk) {
    const int total  = cnt[0];
    const int lane   = threadIdx.x & 63;
    const int wid    = (blockIdx.x * 256 + threadIdx.x) >> 6;
    const int nwaves = (gridDim.x * 256) >> 6;

    for (int i = wid; i < total; i += nwaves) {
        const int n  = list[i];
        const int b  = n >> 12, wh = n & 4095;
        const float* zp = z_e + (size_t)b * CWH + wh;
        float z[CDIM];
#pragma unroll
        for (int c = 0; c < CDIM; ++c) z[c] = zp[c * WH];

        float best = 1e30f; int bk = 0;
        const int kbase = lane * 16;
#pragma unroll 4
        for (int j = 0; j < 16; ++j) {
            const int k = kbase + j;
            const float4* er4 = (const float4*)(emb + k * CDIM);
            float d0 = 0.f, d1 = 0.f, d2 = 0.f, d3 = 0.f;
#pragma unroll
            for (int c4 = 0; c4 < CDIM / 4; ++c4) {
                float4 v = er4[c4];
                d0 = fmaf(z[4 * c4 + 0], v.x, d0);
                d1 = fmaf(z[4 * c4 + 1], v.y, d1);
                d2 = fmaf(z[4 * c4 + 2], v.z, d2);
                d3 = fmaf(z[4 * c4 + 3], v.w, d3);
            }
            float dot   = (d0 + d1) + (d2 + d3);
            float score = fmaf(-2.0f, dot, E[k]);
            if (score < best) { best = score; bk = k; }
        }
#pragma unroll
        for (int d = 1; d < 64; d <<= 1) {
            float ob = __shfl_xor(best, d);
            int   ok = __shfl_xor(bk, d);
            if (ob < best || (ob == best && ok < bk)) { best = ob; bk = ok; }
        }
        if (lane == 0) bestk[n] = bk;
    }
}

// ---------- gather + q/idx write + loss: 2 threads/point (R10 verbatim) ----------
__global__ __launch_bounds__(256) void vq_merge(const float* __restrict__ z_e,
                                                const float* __restrict__ emb,
                                                const int* __restrict__ kf,
                                                float* __restrict__ out_q,
                                                float* __restrict__ out_idx,
                                                float* __restrict__ partials) {
    const int tid  = threadIdx.x;
    const int half = tid >> 7;          // 0: channels 0-31, 1: channels 32-63
    const int pl   = tid & 127;
    const int n    = blockIdx.x * 128 + pl;
    const int b    = n >> 12;
    const int wh   = n & 4095;

    int mk = kf[n];
    if (half == 0) out_idx[n] = (float)mk;

    const float* eb = emb + mk * CDIM + half * 32;
    const float* zp = z_e + (size_t)b * CWH + (size_t)(half * 32) * WH + wh;
    float*       qp = out_q + (size_t)b * CWH + (size_t)(half * 32) * WH + wh;
    float lsum = 0.f;
#pragma unroll
    for (int c = 0; c < 32; ++c) {
        float ev = eb[c];
        qp[(size_t)c * WH] = ev;
        float d = ev - zp[(size_t)c * WH];
        lsum = fmaf(d, d, lsum);
    }

    __shared__ float red[256];
    red[tid] = lsum;
    __syncthreads();
    for (int s = 128; s > 0; s >>= 1) {
        if (tid < s) red[tid] += red[tid + s];
        __syncthreads();
    }
    if (tid == 0) partials[blockIdx.x] = red[0];
}

__global__ __launch_bounds__(1024) void vq_loss_fin(const float* __restrict__ partials,
                                                    float* __restrict__ loss) {
    __shared__ float red[1024];
    int t = threadIdx.x;
    red[t] = partials[t];
    __syncthreads();
    for (int s = 512; s > 0; s >>= 1) {
        if (t < s) red[t] += red[t + s];
        __syncthreads();
    }
    if (t == 0) loss[0] = red[0] * (1.25f / 8388608.0f);
}

extern "C" void kernel_launch(void* const* d_in, const int* in_sizes, int n_in,
                              void* d_out, int out_size, void* d_ws, size_t ws_size,
                              hipStream_t stream) {
    const float* z_e = (const float*)d_in[0];
    const float* emb = (const float*)d_in[1];

    float* out      = (float*)d_out;
    float* out_q    = out;
    float* out_idx  = out + 8388608;
    float* out_loss = out + 8388608 + 131072;

    char* w = (char*)d_ws;
    float*          E        = (float*)(w);                    //   4 KB
    unsigned short* e_swz    = (unsigned short*)(w + 4096);    // 256 KB
    int*            bestk    = (int*)(w + 266240);             // 512 KB
    int*            flagA    = (int*)(w + 790528);             // 512 KB
    int*            list     = (int*)(w + 1314816);            // 512 KB
    int*            cnt      = (int*)(w + 1839104);            //   4 B
    float*          partials = (float*)(w + 1840128);          //   4 KB

    vq_prep<<<KCODES / 256, 256, 0, stream>>>(emb, e_swz, E, cnt);
    vq_scan_mfma<<<NPTS / 128, 256, 0, stream>>>(z_e, e_swz, E, bestk, flagA);
    vq_compact<<<NPTS / 256, 256, 0, stream>>>(flagA, list, cnt);
    vq_rescue<<<2048, 256, 0, stream>>>(z_e, emb, E, list, cnt, bestk);
    vq_merge<<<NPTS / 128, 256, 0, stream>>>(z_e, emb, bestk, out_q, out_idx, partials);
    vq_loss_fin<<<1, 1024, 0, stream>>>(partials, out_loss);
}

// Round 12
// 153.916 us; speedup vs baseline: 1.0521x; 1.0521x over previous
//
#include <hip/hip_runtime.h>

// VQ codebook: z_e [32,64,64,64] f32 (B,C,W,H), emb [1024,64] f32.
// Outputs: quantized [32,64,64,64] f32, indices [131072] (as f32), vq_loss [1].
//
// R12: scan/compact/rescue = R10 verbatim (scan: direct L2 e-loads + register
// prefetch; dbuf/LDS staging measured neutral 3x -> dropped). New:
//  - merge: thread = 4 consecutive points x 8 channels -> float4 z/q accesses,
//    512B contiguous per wave-instr (was 256B scalar). Same emb gather volume.
//    Indices/q values identical; loss partial order changes (mean, allowed).
//  - prep: 8192 threads, ushort8 swizzle stores (was 1024 threads / scalar u16).
//    E[k] arithmetic bit-identical to R1 (scan+rescue consume it).

#define CDIM   64
#define KCODES 1024
#define NPTS   131072
#define WH     4096
#define CWH    262144
#define CTILES (KCODES / 16)     // 64
#define DELTA  0.02f

typedef __attribute__((ext_vector_type(4))) float f32x4;
typedef __attribute__((ext_vector_type(8))) short bf16x8;
typedef __attribute__((ext_vector_type(8))) unsigned short u16x8;

__device__ inline unsigned short f2bf(float f) {
    unsigned u = __float_as_uint(f);
    return (unsigned short)((u + 0x7FFFu + ((u >> 16) & 1u)) >> 16);
}
__device__ inline float bf2f(unsigned short h) {
    return __uint_as_float(((unsigned)h) << 16);
}

// ---------- prep: E (exact R1 order, first 1024 ids) + wide swizzle + cnt=0 ----------
__global__ __launch_bounds__(256) void vq_prep(const float* __restrict__ emb,
                                               unsigned short* __restrict__ e_swz,
                                               float* __restrict__ E,
                                               int* __restrict__ cnt) {
    const int id = blockIdx.x * 256 + threadIdx.x;
    if (id == 0) cnt[0] = 0;

    if (id < KCODES) {   // E[c], bit-identical to R1
        const int c = id;
        const float4* e4 = (const float4*)(emb + c * CDIM);
        float s = 0.f;
#pragma unroll
        for (int i = 0; i < CDIM / 4; ++i) {
            float4 v = e4[i];
            s = fmaf(v.x, v.x, s); s = fmaf(v.y, v.y, s);
            s = fmaf(v.z, v.z, s); s = fmaf(v.w, v.w, s);
        }
        E[c] = s;
    }

    if (id < KCODES * 8) {
        const int c  = id >> 3;
        const int kh = (id >> 2) & 1;
        const int g  = id & 3;
        const int ct = c >> 4, col = c & 15;
        const int lane = (g << 4) | col;
        const size_t bh = ((size_t)(ct * 2 + 0) * 2 + kh) * 512 + (size_t)lane * 8;
        const size_t bl = ((size_t)(ct * 2 + 1) * 2 + kh) * 512 + (size_t)lane * 8;
        u16x8 his, los;
#pragma unroll
        for (int j = 0; j < 8; ++j) {
            float v = emb[c * CDIM + kh * 32 + g * 8 + j];
            unsigned short hi = f2bf(v);
            unsigned short lo = f2bf(v - bf2f(hi));
            his[j] = hi;
            los[j] = lo;
        }
        *(u16x8*)&e_swz[bh] = his;
        *(u16x8*)&e_swz[bl] = los;
    }
}

// ---------- MFMA scan (R10 verbatim): direct e-loads + register prefetch ----------
__global__ __launch_bounds__(256) void vq_scan_mfma(const float* __restrict__ z_e,
                                                    const unsigned short* __restrict__ e_swz,
                                                    const float* __restrict__ E,
                                                    int* __restrict__ bestk,
                                                    int* __restrict__ flagA) {
    const int tid = threadIdx.x;
    const int n0  = blockIdx.x * 128;
    const int b   = n0 >> 12;
    const int wh0 = n0 & 4095;

    __shared__ unsigned short zfrag[8][2][2][512];   // 32 KB

    const float* zp = z_e + (size_t)b * CWH + wh0;
#pragma unroll 4
    for (int i = 0; i < 32; ++i) {
        int flat = i * 256 + tid;
        int c = flat >> 7, p = flat & 127;
        float v = zp[(size_t)c * WH + p];
        unsigned short hi = f2bf(v);
        unsigned short lo = f2bf(v - bf2f(hi));
        int slot = ((((c & 31) >> 3) << 4) | (p & 15)) * 8 + (c & 7);
        zfrag[p >> 4][0][c >> 5][slot] = hi;
        zfrag[p >> 4][1][c >> 5][slot] = lo;
    }
    __syncthreads();

    const int lane = tid & 63;
    const int w    = tid >> 6;

    bf16x8 zf[2][2][2];
#pragma unroll
    for (int pt = 0; pt < 2; ++pt)
#pragma unroll
        for (int s = 0; s < 2; ++s)
#pragma unroll
            for (int kh = 0; kh < 2; ++kh)
                zf[pt][s][kh] = *(const bf16x8*)&zfrag[2 * w + pt][s][kh][lane * 8];

    const bf16x8* ebv = (const bf16x8*)e_swz;
    const int eoff = ((lane >> 4) << 2);

    float m1a = 1e30f, m2a = 1e30f; int k1a = 0;
    float m1b = 1e30f, m2b = 1e30f; int k1b = 0;

    bf16x8 eh0 = ebv[0 * 64 + lane];
    bf16x8 eh1 = ebv[1 * 64 + lane];
    bf16x8 el0 = ebv[2 * 64 + lane];
    bf16x8 el1 = ebv[3 * 64 + lane];
    f32x4  Ev  = *(const f32x4*)(E + eoff);

    for (int ct = 0; ct < CTILES; ++ct) {
        const int ctn = (ct + 1) & 63;
        bf16x8 p0 = ebv[(ctn * 4 + 0) * 64 + lane];
        bf16x8 p1 = ebv[(ctn * 4 + 1) * 64 + lane];
        bf16x8 p2 = ebv[(ctn * 4 + 2) * 64 + lane];
        bf16x8 p3 = ebv[(ctn * 4 + 3) * 64 + lane];
        f32x4  Ep = *(const f32x4*)(E + ctn * 16 + eoff);

        f32x4 acc0 = {0.f, 0.f, 0.f, 0.f};
        f32x4 acc1 = {0.f, 0.f, 0.f, 0.f};
        acc0 = __builtin_amdgcn_mfma_f32_16x16x32_bf16(eh0, zf[0][0][0], acc0, 0, 0, 0);
        acc0 = __builtin_amdgcn_mfma_f32_16x16x32_bf16(eh1, zf[0][0][1], acc0, 0, 0, 0);
        acc0 = __builtin_amdgcn_mfma_f32_16x16x32_bf16(eh0, zf[0][1][0], acc0, 0, 0, 0);
        acc0 = __builtin_amdgcn_mfma_f32_16x16x32_bf16(eh1, zf[0][1][1], acc0, 0, 0, 0);
        acc0 = __builtin_amdgcn_mfma_f32_16x16x32_bf16(el0, zf[0][0][0], acc0, 0, 0, 0);
        acc0 = __builtin_amdgcn_mfma_f32_16x16x32_bf16(el1, zf[0][0][1], acc0, 0, 0, 0);
        acc1 = __builtin_amdgcn_mfma_f32_16x16x32_bf16(eh0, zf[1][0][0], acc1, 0, 0, 0);
        acc1 = __builtin_amdgcn_mfma_f32_16x16x32_bf16(eh1, zf[1][0][1], acc1, 0, 0, 0);
        acc1 = __builtin_amdgcn_mfma_f32_16x16x32_bf16(eh0, zf[1][1][0], acc1, 0, 0, 0);
        acc1 = __builtin_amdgcn_mfma_f32_16x16x32_bf16(eh1, zf[1][1][1], acc1, 0, 0, 0);
        acc1 = __builtin_amdgcn_mfma_f32_16x16x32_bf16(el0, zf[1][0][0], acc1, 0, 0, 0);
        acc1 = __builtin_amdgcn_mfma_f32_16x16x32_bf16(el1, zf[1][0][1], acc1, 0, 0, 0);

        const int kb = ct * 16 + eoff;
#pragma unroll
        for (int i = 0; i < 4; ++i) {
            float s0 = fmaf(-2.0f, acc0[i], Ev[i]);
            if (s0 < m1a) { m2a = m1a; m1a = s0; k1a = kb + i; } else m2a = fminf(m2a, s0);
            float s1 = fmaf(-2.0f, acc1[i], Ev[i]);
            if (s1 < m1b) { m2b = m1b; m1b = s1; k1b = kb + i; } else m2b = fminf(m2b, s1);
        }

        eh0 = p0; eh1 = p1; el0 = p2; el1 = p3; Ev = Ep;
    }

#pragma unroll
    for (int d = 16; d <= 32; d <<= 1) {
        float om1 = __shfl_xor(m1a, d); int ok1 = __shfl_xor(k1a, d); float om2 = __shfl_xor(m2a, d);
        bool take = (om1 < m1a) || (om1 == m1a && ok1 < k1a);
        float nm2 = take ? fminf(m1a, om2) : fminf(m2a, om1);
        if (take) { m1a = om1; k1a = ok1; }
        m2a = nm2;
        om1 = __shfl_xor(m1b, d); ok1 = __shfl_xor(k1b, d); om2 = __shfl_xor(m2b, d);
        take = (om1 < m1b) || (om1 == m1b && ok1 < k1b);
        nm2 = take ? fminf(m1b, om2) : fminf(m2b, om1);
        if (take) { m1b = om1; k1b = ok1; }
        m2b = nm2;
    }

    if (lane < 16) {
        int na  = n0 + (2 * w + 0) * 16 + lane;
        int nb_ = n0 + (2 * w + 1) * 16 + lane;
        bestk[na]  = k1a; flagA[na]  = (m2a - m1a <= DELTA) ? 1 : 0;
        bestk[nb_] = k1b; flagA[nb_] = (m2b - m1b <= DELTA) ? 1 : 0;
    }
}

// ---------- rescue plumbing (R10 verbatim) ----------
__global__ __launch_bounds__(256) void vq_compact(const int* __restrict__ flagA,
                                                  int* __restrict__ list,
                                                  int* __restrict__ cnt) {
    int n = blockIdx.x * 256 + threadIdx.x;
    if (n < NPTS && flagA[n]) { int p = atomicAdd(cnt, 1); list[p] = n; }
}

__global__ __launch_bounds__(256) void vq_rescue(const float* __restrict__ z_e,
                                                 const float* __restrict__ emb,
                                                 const float* __restrict__ E,
                                                 const int* __restrict__ list,
                                                 const int* __restrict__ cnt,
                                                 int* __restrict__ bestk) {
    const int total  = cnt[0];
    const int lane   = threadIdx.x & 63;
    const int wid    = (blockIdx.x * 256 + threadIdx.x) >> 6;
    const int nwaves = (gridDim.x * 256) >> 6;

    for (int i = wid; i < total; i += nwaves) {
        const int n  = list[i];
        const int b  = n >> 12, wh = n & 4095;
        const float* zp = z_e + (size_t)b * CWH + wh;
        float z[CDIM];
#pragma unroll
        for (int c = 0; c < CDIM; ++c) z[c] = zp[c * WH];

        float best = 1e30f; int bk = 0;
        const int kbase = lane * 16;
#pragma unroll 4
        for (int j = 0; j < 16; ++j) {
            const int k = kbase + j;
            const float4* er4 = (const float4*)(emb + k * CDIM);
            float d0 = 0.f, d1 = 0.f, d2 = 0.f, d3 = 0.f;
#pragma unroll
            for (int c4 = 0; c4 < CDIM / 4; ++c4) {
                float4 v = er4[c4];
                d0 = fmaf(z[4 * c4 + 0], v.x, d0);
                d1 = fmaf(z[4 * c4 + 1], v.y, d1);
                d2 = fmaf(z[4 * c4 + 2], v.z, d2);
                d3 = fmaf(z[4 * c4 + 3], v.w, d3);
            }
            float dot   = (d0 + d1) + (d2 + d3);
            float score = fmaf(-2.0f, dot, E[k]);
            if (score < best) { best = score; bk = k; }
        }
#pragma unroll
        for (int d = 1; d < 64; d <<= 1) {
            float ob = __shfl_xor(best, d);
            int   ok = __shfl_xor(bk, d);
            if (ob < best || (ob == best && ok < bk)) { best = ob; bk = ok; }
        }
        if (lane == 0) bestk[n] = bk;
    }
}

// ---------- merge: 4 consecutive points x 8 channels per thread ----------
__global__ __launch_bounds__(256) void vq_merge(const float* __restrict__ z_e,
                                                const float* __restrict__ emb,
                                                const int* __restrict__ kf,
                                                float* __restrict__ out_q,
                                                float* __restrict__ out_idx,
                                                float* __restrict__ partials) {
    const int tid = threadIdx.x;
    const int cq  = tid >> 5;            // 0..7 -> channels cq*8 .. cq*8+7
    const int pq  = tid & 31;            // 4 consecutive points
    const int n0  = blockIdx.x * 128 + pq * 4;
    const int b   = n0 >> 12;            // 128 | 4096: block within one b
    const int wh  = n0 & 4095;

    const int4 mk4 = *(const int4*)&kf[n0];
    if (cq == 0) {
        float4 fx = { (float)mk4.x, (float)mk4.y, (float)mk4.z, (float)mk4.w };
        *(float4*)&out_idx[n0] = fx;
    }

    const float* zb = z_e   + (size_t)b * CWH + wh;
    float*       qb = out_q + (size_t)b * CWH + wh;
    const int c0 = cq * 8;
    float lsum = 0.f;
#pragma unroll
    for (int cc = 0; cc < 8; ++cc) {
        const int c = c0 + cc;
        float4 z4 = *(const float4*)&zb[(size_t)c * WH];
        float4 q4;
        q4.x = emb[mk4.x * CDIM + c];
        q4.y = emb[mk4.y * CDIM + c];
        q4.z = emb[mk4.z * CDIM + c];
        q4.w = emb[mk4.w * CDIM + c];
        *(float4*)&qb[(size_t)c * WH] = q4;
        float dx = q4.x - z4.x, dy = q4.y - z4.y;
        float dz = q4.z - z4.z, dw = q4.w - z4.w;
        lsum = fmaf(dx, dx, lsum); lsum = fmaf(dy, dy, lsum);
        lsum = fmaf(dz, dz, lsum); lsum = fmaf(dw, dw, lsum);
    }

    __shared__ float red[256];
    red[tid] = lsum;
    __syncthreads();
    for (int s = 128; s > 0; s >>= 1) {
        if (tid < s) red[tid] += red[tid + s];
        __syncthreads();
    }
    if (tid == 0) partials[blockIdx.x] = red[0];
}

__global__ __launch_bounds__(1024) void vq_loss_fin(const float* __restrict__ partials,
                                                    float* __restrict__ loss) {
    __shared__ float red[1024];
    int t = threadIdx.x;
    red[t] = partials[t];
    __syncthreads();
    for (int s = 512; s > 0; s >>= 1) {
        if (t < s) red[t] += red[t + s];
        __syncthreads();
    }
    if (t == 0) loss[0] = red[0] * (1.25f / 8388608.0f);
}

extern "C" void kernel_launch(void* const* d_in, const int* in_sizes, int n_in,
                              void* d_out, int out_size, void* d_ws, size_t ws_size,
                              hipStream_t stream) {
    const float* z_e = (const float*)d_in[0];
    const float* emb = (const float*)d_in[1];

    float* out      = (float*)d_out;
    float* out_q    = out;
    float* out_idx  = out + 8388608;
    float* out_loss = out + 8388608 + 131072;

    char* w = (char*)d_ws;
    float*          E        = (float*)(w);                    //   4 KB
    unsigned short* e_swz    = (unsigned short*)(w + 4096);    // 256 KB
    int*            bestk    = (int*)(w + 266240);             // 512 KB
    int*            flagA    = (int*)(w + 790528);             // 512 KB
    int*            list     = (int*)(w + 1314816);            // 512 KB
    int*            cnt      = (int*)(w + 1839104);            //   4 B
    float*          partials = (float*)(w + 1840128);          //   4 KB

    vq_prep<<<32, 256, 0, stream>>>(emb, e_swz, E, cnt);
    vq_scan_mfma<<<NPTS / 128, 256, 0, stream>>>(z_e, e_swz, E, bestk, flagA);
    vq_compact<<<NPTS / 256, 256, 0, stream>>>(flagA, list, cnt);
    vq_rescue<<<2048, 256, 0, stream>>>(z_e, emb, E, list, cnt, bestk);
    vq_merge<<<NPTS / 128, 256, 0, stream>>>(z_e, emb, bestk, out_q, out_idx, partials);
    vq_loss_fin<<<1, 1024, 0, stream>>>(partials, out_loss);
}